// Round 11
// baseline (2226.438 us; speedup 1.0000x reference)
//
#include <hip/hip_runtime.h>

#define B_SZ   256
#define T_SZ   1000
#define N_IN   128
#define UNITS  512
#define NT     76                  // tail rows cached in LDS (436..511)
#define TST    (UNITS - NT)        // 436: first cached row

// dynamic LDS layout (4B words):
//   [0, 39424)   float lds_w[77][512]  (Wz rows 436..511 + zero row 76)
//   [39424, ...) int   list[528]; int s_cnt[8]; int s_cntlo[8]; int s_total
#define SMEM_BYTES ((77 * UNITS + 528 + 8 + 8 + 4) * 4)

// ---------------------------------------------------------------------------
// Phase 0: Wz[513][512]: W_rec with diag zeroed + all-zero row 512. Pad-slot
// (idx 512) and diagonal reads give exact +0.0f (proven r5..r10, absmax 0.0).
// ---------------------------------------------------------------------------
__global__ __launch_bounds__(512) void wz_prep(const float* __restrict__ Wr,
                                               float* __restrict__ Wz) {
    const int c = threadIdx.x, r = blockIdx.x;
    Wz[(size_t)r * UNITS + c] =
        (r >= UNITS || r == c) ? 0.0f : Wr[(size_t)r * UNITS + c];
}

// ---------------------------------------------------------------------------
// Phase 1: C[M,512] = X[M,128] @ W[128,512]  (unchanged, ~fp32 roofline)
// ---------------------------------------------------------------------------
__global__ __launch_bounds__(256) void gemm_in(const float* __restrict__ X,
                                               const float* __restrict__ W,
                                               float* __restrict__ C) {
    __shared__ __align__(16) float As[32][128];
    __shared__ __align__(16) float Bs[32][128];

    const int tid = threadIdx.x;
    const int ntile = blockIdx.x & 3;
    const int mtile = blockIdx.x >> 2;
    const int m0 = mtile * 128, n0 = ntile * 128;
    const int tm  = (tid >> 4) * 8;
    const int tn4 = (tid & 15) * 4;

    float acc[8][8];
#pragma unroll
    for (int i = 0; i < 8; ++i)
#pragma unroll
        for (int j = 0; j < 8; ++j) acc[i][j] = 0.0f;

    for (int k0 = 0; k0 < 128; k0 += 32) {
        __syncthreads();
#pragma unroll
        for (int r = 0; r < 4; ++r) {
            int li  = r * 256 + tid;
            int row = li >> 3;
            int ch  = li & 7;
            float4 a = *(const float4*)&X[(size_t)(m0 + row) * 128 + k0 + ch * 4];
            As[ch * 4 + 0][row] = a.x;
            As[ch * 4 + 1][row] = a.y;
            As[ch * 4 + 2][row] = a.z;
            As[ch * 4 + 3][row] = a.w;
        }
#pragma unroll
        for (int r = 0; r < 4; ++r) {
            int li = r * 256 + tid;
            int kk = li >> 5;
            int n4 = li & 31;
            *(float4*)&Bs[kk][n4 * 4] =
                *(const float4*)&W[(size_t)(k0 + kk) * 512 + n0 + n4 * 4];
        }
        __syncthreads();

#pragma unroll 8
        for (int k = 0; k < 32; ++k) {
            float4 a0 = *(const float4*)&As[k][tm];
            float4 a1 = *(const float4*)&As[k][tm + 4];
            float4 b0 = *(const float4*)&Bs[k][tn4];
            float4 b1 = *(const float4*)&Bs[k][tn4 + 64];
            const float av[8] = {a0.x, a0.y, a0.z, a0.w, a1.x, a1.y, a1.z, a1.w};
            const float bv[8] = {b0.x, b0.y, b0.z, b0.w, b1.x, b1.y, b1.z, b1.w};
#pragma unroll
            for (int i = 0; i < 8; ++i)
#pragma unroll
                for (int j = 0; j < 8; ++j)
                    acc[i][j] = fmaf(av[i], bv[j], acc[i][j]);
        }
    }

#pragma unroll
    for (int i = 0; i < 8; ++i) {
        size_t row = (size_t)(m0 + tm + i) * 512;
        float4 c0 = make_float4(acc[i][0], acc[i][1], acc[i][2], acc[i][3]);
        float4 c1 = make_float4(acc[i][4], acc[i][5], acc[i][6], acc[i][7]);
        *(float4*)&C[row + n0 + tn4]      = c0;
        *(float4*)&C[row + n0 + 64 + tn4] = c1;
    }
}

// ---------------------------------------------------------------------------
// Phase 2: ALIF scan. One WG per batch (grid 256, 512 thr), thread u owns
// unit u. The scan is pinned at the chip-wide L2 BW wall (r1..r10 all at
// ~34 TB/s aggregate), so this round cuts L2 traffic 14.8%: the LAST 76 rows
// of Wz live in LDS (155 KB). Ascending list => actives j>=436 are the list
// TAIL: the L2 loop (r1's exact 8-in-flight shape) runs FIRST over the
// prefix [0, s_lo) — loads start immediately, unlike r9's blocked structure —
// and the LDS tail loop runs last, overlapping the L2 drain.
// Numerics: single acc, globally ascending j; prefix slots >= s_lo select
// the Wz zero row (+0.0f), tail slots < s_lo and pads select LDS zero row 76
// (+0.0f) — bit-identical to all passing rounds (absmax 0.0).
// ---------------------------------------------------------------------------
__global__ __launch_bounds__(512, 1) void alif_scan(const float* __restrict__ Wz,
                                                    float* __restrict__ IO) {
    extern __shared__ __align__(16) float smem[];
    float* lds_w   = smem;                             // [77][512]
    int*   lst     = (int*)(smem + 77 * UNITS);        // [528]
    int*   s_cnt   = lst + 528;                        // [8]
    int*   s_cntlo = s_cnt + 8;                        // [8]
    int*   s_total = s_cntlo + 8;                      // [1]

    const int b = blockIdx.x;
    const int u = threadIdx.x;
    const int w = u >> 6;
    const int lane = u & 63;

    const float DECAY   = 0.95122942450071400910f;   // exp(-1/20)
    const float OMD     = 1.0f - DECAY;
    const float DECAY_B = 0.99501247919268232342f;   // exp(-1/200)
    const float OMDB    = 1.0f - DECAY_B;

    // lanes of this wave whose unit id is < TST (436): wave 6 straddles
    const unsigned long long lomask =
        (w < 6) ? ~0ull : ((w == 6) ? ((1ull << (TST - 384)) - 1ull) : 0ull);

    float v = 0.0f, ad = 0.0f, z = 0.0f;

    const float* wz = Wz + u;                         // column u of Wz
    float* io = IO + (size_t)b * (T_SZ * UNITS) + u;

    // ---- one-time init: stage tail rows 436..511 + zero row 76 ----
    for (int idx = u; idx < 77 * UNITS; idx += 512) {
        int row = idx >> 9;
        lds_w[idx] = (row < NT) ? Wz[(size_t)(TST + row) * UNITS + (idx & 511)]
                                : 0.0f;
    }
    lst[u] = UNITS;
    if (u < 16) lst[UNITS + u] = UNITS;
    if (u < 8) { s_cnt[u] = 0; s_cntlo[u] = 0; }
    if (u == 0) *s_total = 0;
    __syncthreads();

    float i_cur = io[0];

    for (int t = 0; t < T_SZ; ++t) {
        // prefetch next step's input current
        float i_next = io[(t + 1 < T_SZ ? t + 1 : t) * UNITS];

        const int cnt = *s_total;
        // count of actives with j < TST (list prefix length)
        int s_lo = 0;
#pragma unroll
        for (int i = 0; i < 8; ++i) s_lo += s_cntlo[i];

        float acc = 0.0f;

        // ---- L2 prefix: r1's proven 8-in-flight loop over j < TST ----
        // slots >= s_lo (tail actives / pads) select the Wz zero row
        for (int k = 0; k < s_lo; k += 8) {
            int4 Ja = *(const int4*)(lst + k);
            int4 Jb = *(const int4*)(lst + k + 4);
            int j0 = (k + 0 < s_lo) ? Ja.x : UNITS;
            int j1 = (k + 1 < s_lo) ? Ja.y : UNITS;
            int j2 = (k + 2 < s_lo) ? Ja.z : UNITS;
            int j3 = (k + 3 < s_lo) ? Ja.w : UNITS;
            int j4 = (k + 4 < s_lo) ? Jb.x : UNITS;
            int j5 = (k + 5 < s_lo) ? Jb.y : UNITS;
            int j6 = (k + 6 < s_lo) ? Jb.z : UNITS;
            int j7 = (k + 7 < s_lo) ? Jb.w : UNITS;
            float g0 = wz[j0 * UNITS], g1 = wz[j1 * UNITS];
            float g2 = wz[j2 * UNITS], g3 = wz[j3 * UNITS];
            float g4 = wz[j4 * UNITS], g5 = wz[j5 * UNITS];
            float g6 = wz[j6 * UNITS], g7 = wz[j7 * UNITS];
            acc = __fadd_rn(acc, g0);
            acc = __fadd_rn(acc, g1);
            acc = __fadd_rn(acc, g2);
            acc = __fadd_rn(acc, g3);
            acc = __fadd_rn(acc, g4);
            acc = __fadd_rn(acc, g5);
            acc = __fadd_rn(acc, g6);
            acc = __fadd_rn(acc, g7);
        }

        // ---- LDS tail: actives j >= TST, zero L2 traffic ----
        // slots < s_lo and pads select LDS zero row 76
        for (int k = s_lo & ~7; k < cnt; k += 8) {
            int4 Ja = *(const int4*)(lst + k);
            int4 Jb = *(const int4*)(lst + k + 4);
            int j0 = (k + 0 >= s_lo) ? min(Ja.x - TST, NT) : NT;
            int j1 = (k + 1 >= s_lo) ? min(Ja.y - TST, NT) : NT;
            int j2 = (k + 2 >= s_lo) ? min(Ja.z - TST, NT) : NT;
            int j3 = (k + 3 >= s_lo) ? min(Ja.w - TST, NT) : NT;
            int j4 = (k + 4 >= s_lo) ? min(Jb.x - TST, NT) : NT;
            int j5 = (k + 5 >= s_lo) ? min(Jb.y - TST, NT) : NT;
            int j6 = (k + 6 >= s_lo) ? min(Jb.z - TST, NT) : NT;
            int j7 = (k + 7 >= s_lo) ? min(Jb.w - TST, NT) : NT;
            float g0 = lds_w[j0 * UNITS + u], g1 = lds_w[j1 * UNITS + u];
            float g2 = lds_w[j2 * UNITS + u], g3 = lds_w[j3 * UNITS + u];
            float g4 = lds_w[j4 * UNITS + u], g5 = lds_w[j5 * UNITS + u];
            float g6 = lds_w[j6 * UNITS + u], g7 = lds_w[j7 * UNITS + u];
            acc = __fadd_rn(acc, g0);
            acc = __fadd_rn(acc, g1);
            acc = __fadd_rn(acc, g2);
            acc = __fadd_rn(acc, g3);
            acc = __fadd_rn(acc, g4);
            acc = __fadd_rn(acc, g5);
            acc = __fadd_rn(acc, g6);
            acc = __fadd_rn(acc, g7);
        }

        // ---- elementwise state update — exact reference op order ----
        float newb = __fadd_rn(__fmul_rn(DECAY_B, ad), __fmul_rn(OMDB, z));
        float thr  = __fadd_rn(0.01f, __fmul_rn(newb, 1.6f));
        float it   = __fadd_rn(__fadd_rn(i_cur, acc), 0.0f);       // + ADD_CUR
        float ires = __fmul_rn(__fmul_rn(z, thr), 1.0f);           // * DT
        float newv = __fsub_rn(
            __fadd_rn(__fmul_rn(DECAY, v), __fmul_rn(OMD, it)), ires);
        float zn = (newv > thr) ? 1.0f : 0.0f;      // refractory is a no-op

        io[t * UNITS] = zn;
        v = newv; ad = newb; z = zn; i_cur = i_next;

        // ---- rebuild contiguous ascending active list (r1 scheme) ----
        unsigned long long m = __ballot(zn > 0.0f);
        if (lane == 0) {
            s_cnt[w]   = __popcll(m);
            s_cntlo[w] = __popcll(m & lomask);
        }
        __syncthreads();   // [A] reads of old list done; counts visible

        int base = 0, total = 0;
#pragma unroll
        for (int i = 0; i < 8; ++i) {
            int c = s_cnt[i];
            total += c;
            if (i < w) base += c;
        }
        if (zn > 0.0f) {
            int pos = base + __popcll(m & ((1ull << lane) - 1ull));
            lst[pos] = u;
        }
        if (u == 0) *s_total = total;
        if (u < 16) lst[total + u] = UNITS;          // pad idx -> zero row
        __syncthreads();   // [C] list ready
    }
}

extern "C" void kernel_launch(void* const* d_in, const int* in_sizes, int n_in,
                              void* d_out, int out_size, void* d_ws, size_t ws_size,
                              hipStream_t stream) {
    (void)in_sizes; (void)n_in; (void)out_size; (void)ws_size;
    const float* x     = (const float*)d_in[0];   // [B,T,128]
    const float* W_in  = (const float*)d_in[1];   // [128,512]
    const float* W_rec = (const float*)d_in[2];   // [512,512]
    float* out = (float*)d_out;                   // [B,T,512]
    float* Wz  = (float*)d_ws;                    // [513][512] zero-diag copy

    wz_prep<<<dim3(UNITS + 1), dim3(UNITS), 0, stream>>>(W_rec, Wz);
    gemm_in<<<dim3((B_SZ * T_SZ / 128) * (UNITS / 128)), dim3(256), 0, stream>>>(
        x, W_in, out);

    hipFuncSetAttribute((const void*)alif_scan,
                        hipFuncAttributeMaxDynamicSharedMemorySize, SMEM_BYTES);
    alif_scan<<<dim3(B_SZ), dim3(512), SMEM_BYTES, stream>>>(Wz, out);
}